// Round 2
// baseline (4256.791 us; speedup 1.0000x reference)
//
#include <hip/hip_runtime.h>
#include <hip/hip_bf16.h>

// Problem constants (match reference)
constexpr int B    = 4;
constexpr int N    = 16384;
constexpr int CIN  = 64;
constexpr int COUT = 128;
constexpr int R    = 32;
constexpr int R3   = R * R * R;          // 32768
constexpr float VOX_EPS   = 1e-6f;
constexpr float BN3D_EPS  = 1e-4f;
constexpr float BN1D_EPS  = 1e-5f;
constexpr float LRELU     = 0.1f;

// ---------------------------------------------------------------------------
// Kernel 1: per-batch mean + max-norm -> stats[b*4] = {mx,my,mz, denom}
// ---------------------------------------------------------------------------
__global__ __launch_bounds__(256) void k_stats(const float* __restrict__ coords,
                                               float* __restrict__ stats) {
    int b = blockIdx.x;
    const float* c = coords + (size_t)b * N * 3;
    __shared__ float sred[256];
    __shared__ float mean[3];

    float sx = 0.f, sy = 0.f, sz = 0.f;
    for (int i = threadIdx.x; i < N; i += 256) {
        sx += c[i * 3 + 0];
        sy += c[i * 3 + 1];
        sz += c[i * 3 + 2];
    }
    float vals[3] = {sx, sy, sz};
    for (int k = 0; k < 3; ++k) {
        sred[threadIdx.x] = vals[k];
        __syncthreads();
        for (int s = 128; s > 0; s >>= 1) {
            if (threadIdx.x < s) sred[threadIdx.x] += sred[threadIdx.x + s];
            __syncthreads();
        }
        if (threadIdx.x == 0) mean[k] = sred[0] / (float)N;
        __syncthreads();
    }
    float mx = mean[0], my = mean[1], mz = mean[2];
    float mmax = 0.f;
    for (int i = threadIdx.x; i < N; i += 256) {
        float dx = c[i * 3 + 0] - mx;
        float dy = c[i * 3 + 1] - my;
        float dz = c[i * 3 + 2] - mz;
        mmax = fmaxf(mmax, sqrtf(dx * dx + dy * dy + dz * dz));
    }
    sred[threadIdx.x] = mmax;
    __syncthreads();
    for (int s = 128; s > 0; s >>= 1) {
        if (threadIdx.x < s) sred[threadIdx.x] = fmaxf(sred[threadIdx.x], sred[threadIdx.x + s]);
        __syncthreads();
    }
    if (threadIdx.x == 0) {
        stats[b * 4 + 0] = mx;
        stats[b * 4 + 1] = my;
        stats[b * 4 + 2] = mz;
        stats[b * 4 + 3] = sred[0] * 2.0f + VOX_EPS;
    }
}

// nc = clip(((c - mean)/denom + 0.5) * R, 0, R-1)
__device__ inline void compute_nc(const float* __restrict__ coords,
                                  const float* __restrict__ stats,
                                  int p, int b, float& nx, float& ny, float& nz) {
    float denom = stats[b * 4 + 3];
    float cx = coords[(size_t)p * 3 + 0];
    float cy = coords[(size_t)p * 3 + 1];
    float cz = coords[(size_t)p * 3 + 2];
    nx = (cx - stats[b * 4 + 0]) / denom + 0.5f;
    ny = (cy - stats[b * 4 + 1]) / denom + 0.5f;
    nz = (cz - stats[b * 4 + 2]) / denom + 0.5f;
    nx = fminf(fmaxf(nx * (float)R, 0.f), (float)(R - 1));
    ny = fminf(fmaxf(ny * (float)R, 0.f), (float)(R - 1));
    nz = fminf(fmaxf(nz * (float)R, 0.f), (float)(R - 1));
}

// ---------------------------------------------------------------------------
// Kernel 2: scatter-add features into grid sums + counts (4 points / block)
// ---------------------------------------------------------------------------
__global__ __launch_bounds__(256) void k_scatter(const float* __restrict__ coords,
                                                 const float* __restrict__ feats,
                                                 const float* __restrict__ stats,
                                                 float* __restrict__ grid,
                                                 float* __restrict__ cnt) {
    int sub = threadIdx.x >> 6;        // 0..3
    int ci  = threadIdx.x & 63;
    int p   = blockIdx.x * 4 + sub;    // point index 0..B*N
    __shared__ int s_lin[4];
    if (ci == 0) {
        int b = p >> 14;               // N = 16384
        float nx, ny, nz;
        compute_nc(coords, stats, p, b, nx, ny, nz);
        int vx = (int)rintf(nx);
        int vy = (int)rintf(ny);
        int vz = (int)rintf(nz);
        int lin = ((b * R + vx) * R + vy) * R + vz;
        s_lin[sub] = lin;
        atomicAdd(&cnt[lin], 1.0f);
    }
    __syncthreads();
    atomicAdd(&grid[(size_t)s_lin[sub] * CIN + ci], feats[(size_t)p * CIN + ci]);
}

// ---------------------------------------------------------------------------
// Kernel 3: grid = sums / max(cnt,1)
// ---------------------------------------------------------------------------
__global__ __launch_bounds__(256) void k_finalize(float* __restrict__ grid,
                                                  const float* __restrict__ cnt) {
    size_t i = (size_t)blockIdx.x * 256 + threadIdx.x;   // B*R3*CIN total
    float c = cnt[i >> 6];
    grid[i] = grid[i] / (c == 0.f ? 1.f : c);
}

// ---------------------------------------------------------------------------
// Kernel 4: 3x3x3 conv (SAME, zero pad) + bias + BN + LeakyReLU
// Block: 128 threads (one per cout) x 8 voxels along z.
// ---------------------------------------------------------------------------
template <int CI>
__global__ __launch_bounds__(128) void k_conv(const float* __restrict__ in,
                                              const float* __restrict__ w,
                                              const float* __restrict__ bias,
                                              const float* __restrict__ bng,
                                              const float* __restrict__ bnb,
                                              const float* __restrict__ bnm,
                                              const float* __restrict__ bnv,
                                              float* __restrict__ out) {
    constexpr int BV = 8;
    constexpr int ZP = BV + 2;    // 10
    constexpr int C4 = CI / 4;

    int bid = blockIdx.x;
    int zt = bid & 3;
    int y  = (bid >> 2) & 31;
    int x  = (bid >> 7) & 31;
    int b  = bid >> 12;
    int z0 = zt * BV;

    __shared__ float sh[9 * ZP * CI];
    float4* sh4 = (float4*)sh;

    constexpr int NV4 = 9 * ZP * C4;
    for (int t = threadIdx.x; t < NV4; t += 128) {
        int c4  = t % C4;
        int pos = t / C4;
        int j   = pos % ZP;
        int row = pos / ZP;          // 0..8
        int xx = x + row / 3 - 1;
        int yy = y + row % 3 - 1;
        int zz = z0 + j - 1;
        float4 v = make_float4(0.f, 0.f, 0.f, 0.f);
        if (xx >= 0 && xx < R && yy >= 0 && yy < R && zz >= 0 && zz < R) {
            v = *(const float4*)&in[((((size_t)b * R + xx) * R + yy) * R + zz) * CI + c4 * 4];
        }
        sh4[t] = v;
    }
    __syncthreads();

    int co = threadIdx.x;
    float acc[BV];
#pragma unroll
    for (int v = 0; v < BV; ++v) acc[v] = 0.f;

#pragma unroll 1
    for (int row = 0; row < 9; ++row) {
        const float4* shrow = sh4 + row * ZP * C4;
        for (int c4 = 0; c4 < C4; ++c4) {
            float4 zv[ZP];
#pragma unroll
            for (int j = 0; j < ZP; ++j) zv[j] = shrow[j * C4 + c4];
#pragma unroll
            for (int dz = 0; dz < 3; ++dz) {
                int tap = row * 3 + dz;
                const float* wp = w + ((size_t)tap * CI + c4 * 4) * COUT + co;
                float w0 = wp[0];
                float w1 = wp[COUT];
                float w2 = wp[2 * COUT];
                float w3 = wp[3 * COUT];
#pragma unroll
                for (int v = 0; v < BV; ++v) {
                    float4 z4 = zv[v + dz];
                    acc[v] += z4.x * w0 + z4.y * w1 + z4.z * w2 + z4.w * w3;
                }
            }
        }
    }

    float sc = bng[co] * rsqrtf(bnv[co] + BN3D_EPS);
    float sb = bnb[co] - bnm[co] * sc;
    float bs = bias[co];
    size_t obase = ((((size_t)b * R + x) * R + y) * R + z0) * COUT + co;
#pragma unroll
    for (int v = 0; v < BV; ++v) {
        float r = (acc[v] + bs) * sc + sb;
        out[obase + (size_t)v * COUT] = r >= 0.f ? r : LRELU * r;
    }
}

// ---------------------------------------------------------------------------
// Kernel 5: trilinear devoxelize + point MLP (1x1 conv + BN + ReLU) + add
// Block: 128 threads (one per cout), one point per block.
// ---------------------------------------------------------------------------
__global__ __launch_bounds__(128) void k_devox(const float* __restrict__ coords,
                                               const float* __restrict__ feats,
                                               const float* __restrict__ stats,
                                               const float* __restrict__ g2,
                                               const float* __restrict__ pw,
                                               const float* __restrict__ pb,
                                               const float* __restrict__ pg,
                                               const float* __restrict__ pbb,
                                               const float* __restrict__ pm,
                                               const float* __restrict__ pv,
                                               float* __restrict__ out) {
    int p = blockIdx.x;
    int b = p >> 14;
    __shared__ float sfeat[CIN];
    __shared__ int   sidx[8];
    __shared__ float sw[8];

    if (threadIdx.x < CIN) sfeat[threadIdx.x] = feats[(size_t)p * CIN + threadIdx.x];
    if (threadIdx.x == 0) {
        float nx, ny, nz;
        compute_nc(coords, stats, p, b, nx, ny, nz);
        int cx0 = (int)floorf(nx), cy0 = (int)floorf(ny), cz0 = (int)floorf(nz);
        float fx = nx - (float)cx0, fy = ny - (float)cy0, fz = nz - (float)cz0;
        int cx1 = min(cx0 + 1, R - 1), cy1 = min(cy0 + 1, R - 1), cz1 = min(cz0 + 1, R - 1);
#pragma unroll
        for (int k = 0; k < 8; ++k) {
            int dx = (k >> 2) & 1, dy = (k >> 1) & 1, dz = k & 1;
            int ix = dx ? cx1 : cx0;
            int iy = dy ? cy1 : cy0;
            int iz = dz ? cz1 : cz0;
            sidx[k] = (((b * R + ix) * R + iy) * R + iz) * COUT;
            sw[k] = (dx ? fx : 1.f - fx) * (dy ? fy : 1.f - fy) * (dz ? fz : 1.f - fz);
        }
    }
    __syncthreads();

    int co = threadIdx.x;
    float acc = 0.f;
#pragma unroll
    for (int k = 0; k < 8; ++k) acc += sw[k] * g2[(size_t)sidx[k] + co];

    float pf = pb[co];
#pragma unroll 8
    for (int ci = 0; ci < CIN; ++ci) pf += sfeat[ci] * pw[ci * COUT + co];
    float sc = pg[co] * rsqrtf(pv[co] + BN1D_EPS);
    pf = (pf - pm[co]) * sc + pbb[co];
    pf = fmaxf(pf, 0.f);

    out[(size_t)p * COUT + co] = acc + pf;
}

// ---------------------------------------------------------------------------
extern "C" void kernel_launch(void* const* d_in, const int* in_sizes, int n_in,
                              void* d_out, int out_size, void* d_ws, size_t ws_size,
                              hipStream_t stream) {
    const float* feats   = (const float*)d_in[0];
    const float* coords  = (const float*)d_in[1];
    const float* conv1_w = (const float*)d_in[2];
    const float* conv1_b = (const float*)d_in[3];
    const float* bn1_g   = (const float*)d_in[4];
    const float* bn1_b   = (const float*)d_in[5];
    const float* bn1_m   = (const float*)d_in[6];
    const float* bn1_v   = (const float*)d_in[7];
    const float* conv2_w = (const float*)d_in[8];
    const float* conv2_b = (const float*)d_in[9];
    const float* bn2_g   = (const float*)d_in[10];
    const float* bn2_b   = (const float*)d_in[11];
    const float* bn2_m   = (const float*)d_in[12];
    const float* bn2_v   = (const float*)d_in[13];
    const float* pw      = (const float*)d_in[14];
    const float* pb      = (const float*)d_in[15];
    const float* pbn_g   = (const float*)d_in[16];
    const float* pbn_b   = (const float*)d_in[17];
    const float* pbn_m   = (const float*)d_in[18];
    const float* pbn_v   = (const float*)d_in[19];

    float* ws    = (float*)d_ws;
    float* stats = ws;                          // 16 floats (pad to 64)
    float* grid  = ws + 64;                     // B*R3*CIN
    float* cnt   = grid + (size_t)B * R3 * CIN; // B*R3
    float* g1    = cnt + (size_t)B * R3;        // B*R3*COUT
    float* g2    = g1 + (size_t)B * R3 * COUT;  // B*R3*COUT
    float* outf  = (float*)d_out;

    // zero grid sums + counts (contiguous)
    hipMemsetAsync(grid, 0, ((size_t)B * R3 * CIN + (size_t)B * R3) * sizeof(float), stream);

    k_stats<<<B, 256, 0, stream>>>(coords, stats);
    k_scatter<<<(B * N) / 4, 256, 0, stream>>>(coords, feats, stats, grid, cnt);
    k_finalize<<<(B * R3 * CIN) / 256, 256, 0, stream>>>(grid, cnt);
    k_conv<CIN><<<B * R * R * (R / 8), 128, 0, stream>>>(grid, conv1_w, conv1_b,
                                                         bn1_g, bn1_b, bn1_m, bn1_v, g1);
    k_conv<COUT><<<B * R * R * (R / 8), 128, 0, stream>>>(g1, conv2_w, conv2_b,
                                                          bn2_g, bn2_b, bn2_m, bn2_v, g2);
    k_devox<<<B * N, 128, 0, stream>>>(coords, feats, stats, g2, pw, pb,
                                       pbn_g, pbn_b, pbn_m, pbn_v, outf);

    // coords passthrough (output 1)
    hipMemcpyAsync(outf + (size_t)B * N * COUT, coords, (size_t)B * N * 3 * sizeof(float),
                   hipMemcpyDeviceToDevice, stream);
}

// Round 3
// 470.493 us; speedup vs baseline: 9.0475x; 9.0475x over previous
//
#include <hip/hip_runtime.h>
#include <hip/hip_bf16.h>

// Problem constants (match reference)
constexpr int B    = 4;
constexpr int N    = 16384;
constexpr int CIN  = 64;
constexpr int COUT = 128;
constexpr int R    = 32;
constexpr int R3   = R * R * R;          // 32768
constexpr float VOX_EPS   = 1e-6f;
constexpr float BN3D_EPS  = 1e-4f;
constexpr float BN1D_EPS  = 1e-5f;
constexpr float LRELU     = 0.1f;

typedef __attribute__((ext_vector_type(8))) short bf16x8;   // 8 bf16 (4 VGPRs)
typedef __attribute__((ext_vector_type(4))) float f32x4;    // MFMA accumulator

__device__ inline float bf2f(ushort u) {
    union { unsigned int i; float f; } x; x.i = ((unsigned int)u) << 16; return x.f;
}
__device__ inline ushort f2bf(float f) {   // round-to-nearest-even
    union { float f; unsigned int i; } x; x.f = f;
    unsigned int r = x.i + 0x7fffu + ((x.i >> 16) & 1u);
    return (ushort)(r >> 16);
}

// ---------------------------------------------------------------------------
// Kernel 1: per-batch mean + max-norm -> stats[b*4] = {mx,my,mz, denom}
// ---------------------------------------------------------------------------
__global__ __launch_bounds__(256) void k_stats(const float* __restrict__ coords,
                                               float* __restrict__ stats) {
    int b = blockIdx.x;
    const float* c = coords + (size_t)b * N * 3;
    __shared__ float sred[256];
    __shared__ float mean[3];

    float sx = 0.f, sy = 0.f, sz = 0.f;
    for (int i = threadIdx.x; i < N; i += 256) {
        sx += c[i * 3 + 0];
        sy += c[i * 3 + 1];
        sz += c[i * 3 + 2];
    }
    float vals[3] = {sx, sy, sz};
    for (int k = 0; k < 3; ++k) {
        sred[threadIdx.x] = vals[k];
        __syncthreads();
        for (int s = 128; s > 0; s >>= 1) {
            if (threadIdx.x < s) sred[threadIdx.x] += sred[threadIdx.x + s];
            __syncthreads();
        }
        if (threadIdx.x == 0) mean[k] = sred[0] / (float)N;
        __syncthreads();
    }
    float mx = mean[0], my = mean[1], mz = mean[2];
    float mmax = 0.f;
    for (int i = threadIdx.x; i < N; i += 256) {
        float dx = c[i * 3 + 0] - mx;
        float dy = c[i * 3 + 1] - my;
        float dz = c[i * 3 + 2] - mz;
        mmax = fmaxf(mmax, sqrtf(dx * dx + dy * dy + dz * dz));
    }
    sred[threadIdx.x] = mmax;
    __syncthreads();
    for (int s = 128; s > 0; s >>= 1) {
        if (threadIdx.x < s) sred[threadIdx.x] = fmaxf(sred[threadIdx.x], sred[threadIdx.x + s]);
        __syncthreads();
    }
    if (threadIdx.x == 0) {
        stats[b * 4 + 0] = mx;
        stats[b * 4 + 1] = my;
        stats[b * 4 + 2] = mz;
        stats[b * 4 + 3] = sred[0] * 2.0f + VOX_EPS;
    }
}

// nc = clip(((c - mean)/denom + 0.5) * R, 0, R-1)
__device__ inline void compute_nc(const float* __restrict__ coords,
                                  const float* __restrict__ stats,
                                  int p, int b, float& nx, float& ny, float& nz) {
    float denom = stats[b * 4 + 3];
    float cx = coords[(size_t)p * 3 + 0];
    float cy = coords[(size_t)p * 3 + 1];
    float cz = coords[(size_t)p * 3 + 2];
    nx = (cx - stats[b * 4 + 0]) / denom + 0.5f;
    ny = (cy - stats[b * 4 + 1]) / denom + 0.5f;
    nz = (cz - stats[b * 4 + 2]) / denom + 0.5f;
    nx = fminf(fmaxf(nx * (float)R, 0.f), (float)(R - 1));
    ny = fminf(fmaxf(ny * (float)R, 0.f), (float)(R - 1));
    nz = fminf(fmaxf(nz * (float)R, 0.f), (float)(R - 1));
}

// ---------------------------------------------------------------------------
// Kernel 2: scatter-add features into fp32 sums + counts (4 points / block)
// ---------------------------------------------------------------------------
__global__ __launch_bounds__(256) void k_scatter(const float* __restrict__ coords,
                                                 const float* __restrict__ feats,
                                                 const float* __restrict__ stats,
                                                 float* __restrict__ sums,
                                                 float* __restrict__ cnt) {
    int sub = threadIdx.x >> 6;        // 0..3
    int ci  = threadIdx.x & 63;
    int p   = blockIdx.x * 4 + sub;    // point index 0..B*N
    __shared__ int s_lin[4];
    if (ci == 0) {
        int b = p >> 14;               // N = 16384
        float nx, ny, nz;
        compute_nc(coords, stats, p, b, nx, ny, nz);
        int vx = (int)rintf(nx);
        int vy = (int)rintf(ny);
        int vz = (int)rintf(nz);
        int lin = ((b * R + vx) * R + vy) * R + vz;
        s_lin[sub] = lin;
        atomicAdd(&cnt[lin], 1.0f);
    }
    __syncthreads();
    atomicAdd(&sums[(size_t)s_lin[sub] * CIN + ci], feats[(size_t)p * CIN + ci]);
}

// ---------------------------------------------------------------------------
// Kernel 3: gridb(bf16) = sums / max(cnt,1)
// ---------------------------------------------------------------------------
__global__ __launch_bounds__(256) void k_finalize(const float* __restrict__ sums,
                                                  const float* __restrict__ cnt,
                                                  ushort* __restrict__ gridb) {
    size_t i = (size_t)blockIdx.x * 256 + threadIdx.x;   // B*R3*CIN total
    float c = cnt[i >> 6];
    gridb[i] = f2bf(sums[i] / (c == 0.f ? 1.f : c));
}

// ---------------------------------------------------------------------------
// Weight swizzle: W (27*CI, COUT) fp32 -> per-lane B-fragment order bf16.
// wq[((g*8 + nt)*64 + lane)*8 + j] = W[k][n], k = g*32 + (lane>>4)*8 + j,
// n = nt*16 + (lane&15).  One coalesced dwordx4 per wave per fragment.
// ---------------------------------------------------------------------------
__global__ __launch_bounds__(256) void k_wq(const float* __restrict__ w,
                                            ushort* __restrict__ wq) {
    int idx = blockIdx.x * 256 + threadIdx.x;
    int j    = idx & 7;
    int lane = (idx >> 3) & 63;
    int nt   = (idx >> 9) & 7;
    int g    = idx >> 12;
    int k = g * 32 + ((lane >> 4) << 3) + j;
    int n = nt * 16 + (lane & 15);
    wq[idx] = f2bf(w[(size_t)k * COUT + n]);
}

// ---------------------------------------------------------------------------
// MFMA implicit-GEMM 3x3x3 conv + bias + BN + LeakyReLU.
// Block = 256 thr (4 waves) = one (b,x,y) column: M=32 (z), N=128 (cout),
// K = 27*CI. Wave w covers cout tiles {2w,2w+1}; M-tiles {0,1}.
// Input slice (34 z x CI) staged in LDS (bf16, +8 pad -> 2-way bank alias, free).
// ---------------------------------------------------------------------------
template <int CI>
__global__ __launch_bounds__(256) void k_conv_mfma(const ushort* __restrict__ in,
                                                   const ushort* __restrict__ wq,
                                                   const float* __restrict__ bias,
                                                   const float* __restrict__ bng,
                                                   const float* __restrict__ bnb,
                                                   const float* __restrict__ bnm,
                                                   const float* __restrict__ bnv,
                                                   ushort* __restrict__ out) {
    constexpr int PAD = 8;
    constexpr int LDW = CI + PAD;
    constexpr int NCH = CI / 32;     // k-chunks per tap
    constexpr int C4  = CI / 4;
    __shared__ __align__(16) ushort sl[34 * LDW];

    int bid = blockIdx.x;
    int y = bid & 31, x = (bid >> 5) & 31, b = bid >> 10;
    int tid = threadIdx.x;
    int wave = tid >> 6, lane = tid & 63, quad = lane >> 4, l16 = lane & 15;

    f32x4 acc[2][2] = {};   // [m-tile][n-tile-local]

    for (int dxdy = 0; dxdy < 9; ++dxdy) {
        int xx = x + dxdy / 3 - 1;
        int yy = y + dxdy % 3 - 1;
        bool valid = (xx >= 0 && xx < R && yy >= 0 && yy < R);
        const ushort* src = in + ((((size_t)b * R + xx) * R + yy) * R) * CI;

        __syncthreads();
        for (int t = tid; t < 34 * C4; t += 256) {
            int j = t / C4, c4 = t - j * C4;
            int zz = j - 1;
            uint2 v = make_uint2(0u, 0u);
            if (valid && zz >= 0 && zz < R)
                v = *(const uint2*)(src + (size_t)zz * CI + c4 * 4);
            *(uint2*)(sl + j * LDW + c4 * 4) = v;
        }
        __syncthreads();

        for (int dz = 0; dz < 3; ++dz) {
            const ushort* arow0 = sl + (l16 + dz) * LDW + quad * 8;
#pragma unroll
            for (int cc = 0; cc < NCH; ++cc) {
                int g = (dxdy * 3 + dz) * NCH + cc;
                const ushort* bp = wq + ((size_t)(g * 8 + wave * 2) * 64 + lane) * 8;
                bf16x8 bf0 = *(const bf16x8*)bp;
                bf16x8 bf1 = *(const bf16x8*)(bp + 64 * 8);
                bf16x8 a0 = *(const bf16x8*)(arow0 + cc * 32);
                bf16x8 a1 = *(const bf16x8*)(arow0 + 16 * LDW + cc * 32);
                acc[0][0] = __builtin_amdgcn_mfma_f32_16x16x32_bf16(a0, bf0, acc[0][0], 0, 0, 0);
                acc[0][1] = __builtin_amdgcn_mfma_f32_16x16x32_bf16(a0, bf1, acc[0][1], 0, 0, 0);
                acc[1][0] = __builtin_amdgcn_mfma_f32_16x16x32_bf16(a1, bf0, acc[1][0], 0, 0, 0);
                acc[1][1] = __builtin_amdgcn_mfma_f32_16x16x32_bf16(a1, bf1, acc[1][1], 0, 0, 0);
            }
        }
    }

    // Epilogue: bias + BN + LeakyReLU, store bf16.
    // C/D layout (m89-verified): col = lane&15 (cout), row = quad*4 + reg (z).
    int co0 = wave * 32 + l16;
    int co1 = co0 + 16;
    float sc0 = bng[co0] * rsqrtf(bnv[co0] + BN3D_EPS);
    float sb0 = bnb[co0] - bnm[co0] * sc0;
    float bs0 = bias[co0];
    float sc1 = bng[co1] * rsqrtf(bnv[co1] + BN3D_EPS);
    float sb1 = bnb[co1] - bnm[co1] * sc1;
    float bs1 = bias[co1];
    size_t obase = (((size_t)(b * R + x) * R + y) * R) * COUT;
#pragma unroll
    for (int mt = 0; mt < 2; ++mt) {
#pragma unroll
        for (int reg = 0; reg < 4; ++reg) {
            int z = mt * 16 + quad * 4 + reg;
            float v0 = (acc[mt][0][reg] + bs0) * sc0 + sb0;
            v0 = v0 >= 0.f ? v0 : LRELU * v0;
            float v1 = (acc[mt][1][reg] + bs1) * sc1 + sb1;
            v1 = v1 >= 0.f ? v1 : LRELU * v1;
            out[obase + (size_t)z * COUT + co0] = f2bf(v0);
            out[obase + (size_t)z * COUT + co1] = f2bf(v1);
        }
    }
}

// ---------------------------------------------------------------------------
// Kernel 5: trilinear devoxelize (bf16 grid) + point MLP + add
// ---------------------------------------------------------------------------
__global__ __launch_bounds__(128) void k_devox(const float* __restrict__ coords,
                                               const float* __restrict__ feats,
                                               const float* __restrict__ stats,
                                               const ushort* __restrict__ g2,
                                               const float* __restrict__ pw,
                                               const float* __restrict__ pb,
                                               const float* __restrict__ pg,
                                               const float* __restrict__ pbb,
                                               const float* __restrict__ pm,
                                               const float* __restrict__ pv,
                                               float* __restrict__ out) {
    int p = blockIdx.x;
    int b = p >> 14;
    __shared__ float sfeat[CIN];
    __shared__ int   sidx[8];
    __shared__ float sw[8];

    if (threadIdx.x < CIN) sfeat[threadIdx.x] = feats[(size_t)p * CIN + threadIdx.x];
    if (threadIdx.x == 0) {
        float nx, ny, nz;
        compute_nc(coords, stats, p, b, nx, ny, nz);
        int cx0 = (int)floorf(nx), cy0 = (int)floorf(ny), cz0 = (int)floorf(nz);
        float fx = nx - (float)cx0, fy = ny - (float)cy0, fz = nz - (float)cz0;
        int cx1 = min(cx0 + 1, R - 1), cy1 = min(cy0 + 1, R - 1), cz1 = min(cz0 + 1, R - 1);
#pragma unroll
        for (int k = 0; k < 8; ++k) {
            int dx = (k >> 2) & 1, dy = (k >> 1) & 1, dz = k & 1;
            int ix = dx ? cx1 : cx0;
            int iy = dy ? cy1 : cy0;
            int iz = dz ? cz1 : cz0;
            sidx[k] = (((b * R + ix) * R + iy) * R + iz) * COUT;
            sw[k] = (dx ? fx : 1.f - fx) * (dy ? fy : 1.f - fy) * (dz ? fz : 1.f - fz);
        }
    }
    __syncthreads();

    int co = threadIdx.x;
    float acc = 0.f;
#pragma unroll
    for (int k = 0; k < 8; ++k) acc += sw[k] * bf2f(g2[(size_t)sidx[k] + co]);

    float pf = pb[co];
#pragma unroll 8
    for (int ci = 0; ci < CIN; ++ci) pf += sfeat[ci] * pw[ci * COUT + co];
    float sc = pg[co] * rsqrtf(pv[co] + BN1D_EPS);
    pf = (pf - pm[co]) * sc + pbb[co];
    pf = fmaxf(pf, 0.f);

    out[(size_t)p * COUT + co] = acc + pf;
}

// ---------------------------------------------------------------------------
extern "C" void kernel_launch(void* const* d_in, const int* in_sizes, int n_in,
                              void* d_out, int out_size, void* d_ws, size_t ws_size,
                              hipStream_t stream) {
    const float* feats   = (const float*)d_in[0];
    const float* coords  = (const float*)d_in[1];
    const float* conv1_w = (const float*)d_in[2];
    const float* conv1_b = (const float*)d_in[3];
    const float* bn1_g   = (const float*)d_in[4];
    const float* bn1_b   = (const float*)d_in[5];
    const float* bn1_m   = (const float*)d_in[6];
    const float* bn1_v   = (const float*)d_in[7];
    const float* conv2_w = (const float*)d_in[8];
    const float* conv2_b = (const float*)d_in[9];
    const float* bn2_g   = (const float*)d_in[10];
    const float* bn2_b   = (const float*)d_in[11];
    const float* bn2_m   = (const float*)d_in[12];
    const float* bn2_v   = (const float*)d_in[13];
    const float* pw      = (const float*)d_in[14];
    const float* pb      = (const float*)d_in[15];
    const float* pbn_g   = (const float*)d_in[16];
    const float* pbn_b   = (const float*)d_in[17];
    const float* pbn_m   = (const float*)d_in[18];
    const float* pbn_v   = (const float*)d_in[19];

    // Workspace layout (bytes)
    char* wsb = (char*)d_ws;
    float*  stats = (float*)wsb;                               // 256 B
    float*  sums  = (float*)(wsb + 256);                       // B*R3*CIN fp32
    float*  cnt   = (float*)(wsb + 256 + (size_t)B*R3*CIN*4);  // B*R3 fp32
    ushort* gridb = (ushort*)(wsb + 256 + (size_t)B*R3*CIN*4 + (size_t)B*R3*4);
    ushort* g1b   = gridb + (size_t)B * R3 * CIN;
    ushort* g2b   = g1b + (size_t)B * R3 * COUT;
    ushort* wq1   = g2b + (size_t)B * R3 * COUT;               // 54*4096 bf16
    ushort* wq2   = wq1 + 54 * 4096;                           // 108*4096 bf16
    float*  outf  = (float*)d_out;

    // zero fp32 sums + counts (contiguous)
    hipMemsetAsync(sums, 0, ((size_t)B * R3 * CIN + (size_t)B * R3) * sizeof(float), stream);

    k_stats<<<B, 256, 0, stream>>>(coords, stats);
    k_scatter<<<(B * N) / 4, 256, 0, stream>>>(coords, feats, stats, sums, cnt);
    k_finalize<<<(B * R3 * CIN) / 256, 256, 0, stream>>>(sums, cnt, gridb);

    k_wq<<<(54 * 4096) / 256, 256, 0, stream>>>(conv1_w, wq1);
    k_wq<<<(108 * 4096) / 256, 256, 0, stream>>>(conv2_w, wq2);

    k_conv_mfma<CIN><<<B * R * R, 256, 0, stream>>>(gridb, wq1, conv1_b,
                                                    bn1_g, bn1_b, bn1_m, bn1_v, g1b);
    k_conv_mfma<COUT><<<B * R * R, 256, 0, stream>>>(g1b, wq2, conv2_b,
                                                     bn2_g, bn2_b, bn2_m, bn2_v, g2b);

    k_devox<<<B * N, 128, 0, stream>>>(coords, feats, stats, g2b, pw, pb,
                                       pbn_g, pbn_b, pbn_m, pbn_v, outf);

    // coords passthrough (output 1)
    hipMemcpyAsync(outf + (size_t)B * N * COUT, coords, (size_t)B * N * 3 * sizeof(float),
                   hipMemcpyDeviceToDevice, stream);
}

// Round 4
// 428.532 us; speedup vs baseline: 9.9334x; 1.0979x over previous
//
#include <hip/hip_runtime.h>
#include <hip/hip_bf16.h>

// Problem constants (match reference)
constexpr int B    = 4;
constexpr int N    = 16384;
constexpr int CIN  = 64;
constexpr int COUT = 128;
constexpr int R    = 32;
constexpr int R3   = R * R * R;          // 32768
constexpr float VOX_EPS   = 1e-6f;
constexpr float BN3D_EPS  = 1e-4f;
constexpr float BN1D_EPS  = 1e-5f;
constexpr float LRELU     = 0.1f;

typedef __attribute__((ext_vector_type(8))) short bf16x8;   // 8 bf16 (4 VGPRs)
typedef __attribute__((ext_vector_type(4))) float f32x4;    // MFMA accumulator

__device__ inline float bf2f(ushort u) {
    union { unsigned int i; float f; } x; x.i = ((unsigned int)u) << 16; return x.f;
}
__device__ inline ushort f2bf(float f) {   // round-to-nearest-even
    union { float f; unsigned int i; } x; x.f = f;
    unsigned int r = x.i + 0x7fffu + ((x.i >> 16) & 1u);
    return (ushort)(r >> 16);
}

// ---------------------------------------------------------------------------
// Kernel 1: per-batch mean + max-norm -> stats[b*4] = {mx,my,mz, denom}
// ---------------------------------------------------------------------------
__global__ __launch_bounds__(256) void k_stats(const float* __restrict__ coords,
                                               float* __restrict__ stats) {
    int b = blockIdx.x;
    const float* c = coords + (size_t)b * N * 3;
    __shared__ float sred[256];
    __shared__ float mean[3];

    float sx = 0.f, sy = 0.f, sz = 0.f;
    for (int i = threadIdx.x; i < N; i += 256) {
        sx += c[i * 3 + 0];
        sy += c[i * 3 + 1];
        sz += c[i * 3 + 2];
    }
    float vals[3] = {sx, sy, sz};
    for (int k = 0; k < 3; ++k) {
        sred[threadIdx.x] = vals[k];
        __syncthreads();
        for (int s = 128; s > 0; s >>= 1) {
            if (threadIdx.x < s) sred[threadIdx.x] += sred[threadIdx.x + s];
            __syncthreads();
        }
        if (threadIdx.x == 0) mean[k] = sred[0] / (float)N;
        __syncthreads();
    }
    float mx = mean[0], my = mean[1], mz = mean[2];
    float mmax = 0.f;
    for (int i = threadIdx.x; i < N; i += 256) {
        float dx = c[i * 3 + 0] - mx;
        float dy = c[i * 3 + 1] - my;
        float dz = c[i * 3 + 2] - mz;
        mmax = fmaxf(mmax, sqrtf(dx * dx + dy * dy + dz * dz));
    }
    sred[threadIdx.x] = mmax;
    __syncthreads();
    for (int s = 128; s > 0; s >>= 1) {
        if (threadIdx.x < s) sred[threadIdx.x] = fmaxf(sred[threadIdx.x], sred[threadIdx.x + s]);
        __syncthreads();
    }
    if (threadIdx.x == 0) {
        stats[b * 4 + 0] = mx;
        stats[b * 4 + 1] = my;
        stats[b * 4 + 2] = mz;
        stats[b * 4 + 3] = sred[0] * 2.0f + VOX_EPS;
    }
}

// nc = clip(((c - mean)/denom + 0.5) * R, 0, R-1)
__device__ inline void compute_nc(const float* __restrict__ coords,
                                  const float* __restrict__ stats,
                                  int p, int b, float& nx, float& ny, float& nz) {
    float denom = stats[b * 4 + 3];
    float cx = coords[(size_t)p * 3 + 0];
    float cy = coords[(size_t)p * 3 + 1];
    float cz = coords[(size_t)p * 3 + 2];
    nx = (cx - stats[b * 4 + 0]) / denom + 0.5f;
    ny = (cy - stats[b * 4 + 1]) / denom + 0.5f;
    nz = (cz - stats[b * 4 + 2]) / denom + 0.5f;
    nx = fminf(fmaxf(nx * (float)R, 0.f), (float)(R - 1));
    ny = fminf(fmaxf(ny * (float)R, 0.f), (float)(R - 1));
    nz = fminf(fmaxf(nz * (float)R, 0.f), (float)(R - 1));
}

// ---------------------------------------------------------------------------
// Kernel 2: scatter-add features into fp32 sums + counts (4 points / block)
// ---------------------------------------------------------------------------
__global__ __launch_bounds__(256) void k_scatter(const float* __restrict__ coords,
                                                 const float* __restrict__ feats,
                                                 const float* __restrict__ stats,
                                                 float* __restrict__ sums,
                                                 float* __restrict__ cnt) {
    int sub = threadIdx.x >> 6;        // 0..3
    int ci  = threadIdx.x & 63;
    int p   = blockIdx.x * 4 + sub;    // point index 0..B*N
    __shared__ int s_lin[4];
    if (ci == 0) {
        int b = p >> 14;               // N = 16384
        float nx, ny, nz;
        compute_nc(coords, stats, p, b, nx, ny, nz);
        int vx = (int)rintf(nx);
        int vy = (int)rintf(ny);
        int vz = (int)rintf(nz);
        int lin = ((b * R + vx) * R + vy) * R + vz;
        s_lin[sub] = lin;
        atomicAdd(&cnt[lin], 1.0f);
    }
    __syncthreads();
    atomicAdd(&sums[(size_t)s_lin[sub] * CIN + ci], feats[(size_t)p * CIN + ci]);
}

// ---------------------------------------------------------------------------
// Kernel 3: gridb(bf16) = sums / max(cnt,1)
// ---------------------------------------------------------------------------
__global__ __launch_bounds__(256) void k_finalize(const float* __restrict__ sums,
                                                  const float* __restrict__ cnt,
                                                  ushort* __restrict__ gridb) {
    size_t i = (size_t)blockIdx.x * 256 + threadIdx.x;   // B*R3*CIN total
    float c = cnt[i >> 6];
    gridb[i] = f2bf(sums[i] / (c == 0.f ? 1.f : c));
}

// ---------------------------------------------------------------------------
// Weight swizzle: W (27*CI, COUT) fp32 -> per-lane B-fragment order bf16.
// wq[((g*8 + nt)*64 + lane)*8 + j] = W[k][n], k = g*32 + (lane>>4)*8 + j,
// n = nt*16 + (lane&15).  One coalesced dwordx4 per wave per fragment.
// ---------------------------------------------------------------------------
__global__ __launch_bounds__(256) void k_wq(const float* __restrict__ w,
                                            ushort* __restrict__ wq) {
    int idx = blockIdx.x * 256 + threadIdx.x;
    int j    = idx & 7;
    int lane = (idx >> 3) & 63;
    int nt   = (idx >> 9) & 7;
    int g    = idx >> 12;
    int k = g * 32 + ((lane >> 4) << 3) + j;
    int n = nt * 16 + (lane & 15);
    wq[idx] = f2bf(w[(size_t)k * COUT + n]);
}

// ---------------------------------------------------------------------------
// MFMA implicit-GEMM 3x3x3 conv + bias + BN + LeakyReLU.
// Block = 256 thr (4 waves): tile M=128 (4 y-adjacent z-columns at (b,x,4Y..4Y+3)),
// N=128 (all couts). Wave (wm,wn) covers m 64*wm..+63, couts 64*wn..+63:
// 4 m-tiles x 4 n-tiles (16x16x32), 16 MFMA per K-chunk per wave.
// Staging: loop over dx (3), stage 6 y-slices x 34 z x CI in LDS with a 16B-chunk
// XOR swizzle (phys = chunk ^ (zrow&7)) -> conflict-free writes and A-reads.
// B-fragments streamed from L2 (wq pre-swizzled), ~884KB per block of 4 columns.
// ---------------------------------------------------------------------------
template <int CI>
__global__ __launch_bounds__(256, 3) void k_conv_mfma(const ushort* __restrict__ in,
                                                      const ushort* __restrict__ wq,
                                                      const float* __restrict__ bias,
                                                      const float* __restrict__ bng,
                                                      const float* __restrict__ bnb,
                                                      const float* __restrict__ bnm,
                                                      const float* __restrict__ bnv,
                                                      ushort* __restrict__ out) {
    constexpr int NCH    = CI / 32;   // K-32-chunks per tap
    constexpr int NCHUNK = CI / 8;    // 16B chunks per channel row
    __shared__ __align__(16) ushort sl[6 * 34 * CI];

    int bid = blockIdx.x;
    int Y = bid & 7;                  // y-group (4 columns)
    int x = (bid >> 3) & 31;
    int b = bid >> 8;
    int y0 = Y * 4;
    int tid = threadIdx.x;
    int wave = tid >> 6, lane = tid & 63, quad = lane >> 4, l16 = lane & 15;
    int wm = wave >> 1, wn = wave & 1;

    f32x4 acc[4][4] = {};   // [m-tile][n-tile]

    for (int dx = 0; dx < 3; ++dx) {
        int xx = x + dx - 1;
        bool vx = (xx >= 0 && xx < R);
        const ushort* srcx = in + ((size_t)(b * R + xx) * R) * R * CI;

        __syncthreads();
        for (int t = tid; t < 6 * 34 * NCHUNK; t += 256) {
            int c   = t % NCHUNK;
            int rem = t / NCHUNK;
            int zrow = rem % 34;
            int s    = rem / 34;
            int yy = y0 - 1 + s;
            int zz = zrow - 1;
            uint4 v = make_uint4(0u, 0u, 0u, 0u);
            if (vx && yy >= 0 && yy < R && zz >= 0 && zz < R)
                v = *(const uint4*)(srcx + ((size_t)yy * R + zz) * CI + c * 8);
            int phys = c ^ (zrow & 7);
            *(uint4*)(sl + ((s * 34 + zrow) * NCHUNK + phys) * 8) = v;
        }
        __syncthreads();

        for (int dy = 0; dy < 3; ++dy) {
            for (int dz = 0; dz < 3; ++dz) {
#pragma unroll
                for (int cc = 0; cc < NCH; ++cc) {
                    int g = ((dx * 3 + dy) * 3 + dz) * NCH + cc;
                    const ushort* bp = wq + ((size_t)(g * 8 + wn * 4) * 64 + lane) * 8;
                    bf16x8 bfr[4], afr[4];
#pragma unroll
                    for (int nt = 0; nt < 4; ++nt)
                        bfr[nt] = *(const bf16x8*)(bp + nt * 512);
#pragma unroll
                    for (int mt = 0; mt < 4; ++mt) {
                        int s    = wm * 2 + (mt >> 1) + dy;          // slice
                        int zrow = ((mt & 1) << 4) + l16 + dz;
                        int c    = cc * 4 + quad;
                        int phys = c ^ (zrow & 7);
                        afr[mt] = *(const bf16x8*)(sl + ((s * 34 + zrow) * NCHUNK + phys) * 8);
                    }
#pragma unroll
                    for (int mt = 0; mt < 4; ++mt)
#pragma unroll
                        for (int nt = 0; nt < 4; ++nt)
                            acc[mt][nt] = __builtin_amdgcn_mfma_f32_16x16x32_bf16(
                                afr[mt], bfr[nt], acc[mt][nt], 0, 0, 0);
                }
            }
        }
    }

    // Epilogue: bias + BN + LeakyReLU, store bf16.
    // C/D layout (m89-verified): col = lane&15 (cout), row = quad*4 + reg (m).
    float sc[4], sb[4], bs[4];
#pragma unroll
    for (int nt = 0; nt < 4; ++nt) {
        int co = wn * 64 + nt * 16 + l16;
        sc[nt] = bng[co] * rsqrtf(bnv[co] + BN3D_EPS);
        sb[nt] = bnb[co] - bnm[co] * sc[nt];
        bs[nt] = bias[co];
    }
#pragma unroll
    for (int mt = 0; mt < 4; ++mt) {
#pragma unroll
        for (int reg = 0; reg < 4; ++reg) {
            int m = wm * 64 + mt * 16 + quad * 4 + reg;
            int i = m >> 5, z = m & 31;
            size_t obase = (((size_t)(b * R + x) * R + (y0 + i)) * R + z) * COUT + wn * 64 + l16;
#pragma unroll
            for (int nt = 0; nt < 4; ++nt) {
                float v = (acc[mt][nt][reg] + bs[nt]) * sc[nt] + sb[nt];
                v = v >= 0.f ? v : LRELU * v;
                out[obase + nt * 16] = f2bf(v);
            }
        }
    }
}

// ---------------------------------------------------------------------------
// Kernel 5: trilinear devoxelize (bf16 grid) + point MLP + add
// ---------------------------------------------------------------------------
__global__ __launch_bounds__(128) void k_devox(const float* __restrict__ coords,
                                               const float* __restrict__ feats,
                                               const float* __restrict__ stats,
                                               const ushort* __restrict__ g2,
                                               const float* __restrict__ pw,
                                               const float* __restrict__ pb,
                                               const float* __restrict__ pg,
                                               const float* __restrict__ pbb,
                                               const float* __restrict__ pm,
                                               const float* __restrict__ pv,
                                               float* __restrict__ out) {
    int p = blockIdx.x;
    int b = p >> 14;
    __shared__ float sfeat[CIN];
    __shared__ int   sidx[8];
    __shared__ float sw[8];

    if (threadIdx.x < CIN) sfeat[threadIdx.x] = feats[(size_t)p * CIN + threadIdx.x];
    if (threadIdx.x == 0) {
        float nx, ny, nz;
        compute_nc(coords, stats, p, b, nx, ny, nz);
        int cx0 = (int)floorf(nx), cy0 = (int)floorf(ny), cz0 = (int)floorf(nz);
        float fx = nx - (float)cx0, fy = ny - (float)cy0, fz = nz - (float)cz0;
        int cx1 = min(cx0 + 1, R - 1), cy1 = min(cy0 + 1, R - 1), cz1 = min(cz0 + 1, R - 1);
#pragma unroll
        for (int k = 0; k < 8; ++k) {
            int dx = (k >> 2) & 1, dy = (k >> 1) & 1, dz = k & 1;
            int ix = dx ? cx1 : cx0;
            int iy = dy ? cy1 : cy0;
            int iz = dz ? cz1 : cz0;
            sidx[k] = (((b * R + ix) * R + iy) * R + iz) * COUT;
            sw[k] = (dx ? fx : 1.f - fx) * (dy ? fy : 1.f - fy) * (dz ? fz : 1.f - fz);
        }
    }
    __syncthreads();

    int co = threadIdx.x;
    float acc = 0.f;
#pragma unroll
    for (int k = 0; k < 8; ++k) acc += sw[k] * bf2f(g2[(size_t)sidx[k] + co]);

    float pf = pb[co];
#pragma unroll 8
    for (int ci = 0; ci < CIN; ++ci) pf += sfeat[ci] * pw[ci * COUT + co];
    float sc = pg[co] * rsqrtf(pv[co] + BN1D_EPS);
    pf = (pf - pm[co]) * sc + pbb[co];
    pf = fmaxf(pf, 0.f);

    out[(size_t)p * COUT + co] = acc + pf;
}

// ---------------------------------------------------------------------------
extern "C" void kernel_launch(void* const* d_in, const int* in_sizes, int n_in,
                              void* d_out, int out_size, void* d_ws, size_t ws_size,
                              hipStream_t stream) {
    const float* feats   = (const float*)d_in[0];
    const float* coords  = (const float*)d_in[1];
    const float* conv1_w = (const float*)d_in[2];
    const float* conv1_b = (const float*)d_in[3];
    const float* bn1_g   = (const float*)d_in[4];
    const float* bn1_b   = (const float*)d_in[5];
    const float* bn1_m   = (const float*)d_in[6];
    const float* bn1_v   = (const float*)d_in[7];
    const float* conv2_w = (const float*)d_in[8];
    const float* conv2_b = (const float*)d_in[9];
    const float* bn2_g   = (const float*)d_in[10];
    const float* bn2_b   = (const float*)d_in[11];
    const float* bn2_m   = (const float*)d_in[12];
    const float* bn2_v   = (const float*)d_in[13];
    const float* pw      = (const float*)d_in[14];
    const float* pb      = (const float*)d_in[15];
    const float* pbn_g   = (const float*)d_in[16];
    const float* pbn_b   = (const float*)d_in[17];
    const float* pbn_m   = (const float*)d_in[18];
    const float* pbn_v   = (const float*)d_in[19];

    // Workspace layout (bytes)
    char* wsb = (char*)d_ws;
    float*  stats = (float*)wsb;                               // 256 B
    float*  sums  = (float*)(wsb + 256);                       // B*R3*CIN fp32
    float*  cnt   = (float*)(wsb + 256 + (size_t)B*R3*CIN*4);  // B*R3 fp32
    ushort* gridb = (ushort*)(wsb + 256 + (size_t)B*R3*CIN*4 + (size_t)B*R3*4);
    ushort* g1b   = gridb + (size_t)B * R3 * CIN;
    ushort* g2b   = g1b + (size_t)B * R3 * COUT;
    ushort* wq1   = g2b + (size_t)B * R3 * COUT;               // 54*4096 bf16
    ushort* wq2   = wq1 + 54 * 4096;                           // 108*4096 bf16
    float*  outf  = (float*)d_out;

    // zero fp32 sums + counts (contiguous)
    hipMemsetAsync(sums, 0, ((size_t)B * R3 * CIN + (size_t)B * R3) * sizeof(float), stream);

    k_stats<<<B, 256, 0, stream>>>(coords, stats);
    k_scatter<<<(B * N) / 4, 256, 0, stream>>>(coords, feats, stats, sums, cnt);
    k_finalize<<<(B * R3 * CIN) / 256, 256, 0, stream>>>(sums, cnt, gridb);

    k_wq<<<(54 * 4096) / 256, 256, 0, stream>>>(conv1_w, wq1);
    k_wq<<<(108 * 4096) / 256, 256, 0, stream>>>(conv2_w, wq2);

    k_conv_mfma<CIN><<<B * R * (R / 4), 256, 0, stream>>>(gridb, wq1, conv1_b,
                                                          bn1_g, bn1_b, bn1_m, bn1_v, g1b);
    k_conv_mfma<COUT><<<B * R * (R / 4), 256, 0, stream>>>(g1b, wq2, conv2_b,
                                                           bn2_g, bn2_b, bn2_m, bn2_v, g2b);

    k_devox<<<B * N, 128, 0, stream>>>(coords, feats, stats, g2b, pw, pb,
                                       pbn_g, pbn_b, pbn_m, pbn_v, outf);

    // coords passthrough (output 1)
    hipMemcpyAsync(outf + (size_t)B * N * COUT, coords, (size_t)B * N * 3 * sizeof(float),
                   hipMemcpyDeviceToDevice, stream);
}